// Round 6
// baseline (401.320 us; speedup 1.0000x reference)
//
#include <hip/hip_runtime.h>
#include <math.h>

// Shapes (fixed by the problem): b=4, c=512, l=4096, 32 groups.
// Inputs/outputs are float32; internal compute path is bf16 MFMA.
#define BB 4
#define CC 512
#define LL 4096
#define NG 32
#define CPG 16
#define EPSV 1e-6f

typedef short s16x8 __attribute__((ext_vector_type(8)));
typedef __bf16 bf8v __attribute__((ext_vector_type(8)));
typedef float f32x4 __attribute__((ext_vector_type(4)));
typedef unsigned short u16;

typedef const __attribute__((address_space(1))) void g1_void;
typedef __attribute__((address_space(3))) void l3_void;

// raw barrier / waitcnt (memory clobber = compiler reorder fence, no vmcnt drain)
#define ASM_SBAR() asm volatile("s_barrier" ::: "memory")
#define ASM_WAITV(N) asm volatile("s_waitcnt vmcnt(" #N ")" ::: "memory")

static __device__ __forceinline__ float bf2f(u16 h) {
    unsigned int u = ((unsigned int)h) << 16;
    union { unsigned int u; float f; } c; c.u = u; return c.f;
}
static __device__ __forceinline__ u16 f2bf(float f) {
    union { float f; unsigned int u; } c; c.f = f;
    unsigned int lsb = (c.u >> 16) & 1u;
    c.u += 0x7fffu + lsb;           // round-to-nearest-even
    return (u16)(c.u >> 16);
}
static __device__ __forceinline__ bf8v ld_bf8(const u16* p) {
    return *reinterpret_cast<const bf8v*>(p);
}
// async global->LDS; HW writes lds_base + lane*16 (wave-uniform base required)
static __device__ __forceinline__ void gload16(const u16* g, u16* l) {
    __builtin_amdgcn_global_load_lds((g1_void*)g, (l3_void*)l, 16, 0, 0);
}

// ---------------- zero rowsum buffer ----------------
__global__ __launch_bounds__(256) void zero_kernel(float* __restrict__ p, int n) {
    int i = blockIdx.x * 256 + threadIdx.x;
    if (i < n) p[i] = 0.f;
}

// ---------------- weight convert: four 512x512 f32 -> bf16 (rows: q,k,v,p) ----------------
__global__ __launch_bounds__(256) void wconv_kernel(const float* __restrict__ w0,
                                                    const float* __restrict__ w1,
                                                    const float* __restrict__ w2,
                                                    const float* __restrict__ w3,
                                                    u16* __restrict__ wbf) {
    int i = blockIdx.x * 256 + threadIdx.x;      // 0..65535 float4 chunks
    int wsel = blockIdx.y;
    const float* src = (wsel == 0) ? w0 : (wsel == 1) ? w1 : (wsel == 2) ? w2 : w3;
    float4 v = reinterpret_cast<const float4*>(src)[i];
    ushort4 o;
    o.x = f2bf(v.x); o.y = f2bf(v.y); o.z = f2bf(v.z); o.w = f2bf(v.w);
    reinterpret_cast<ushort4*>(wbf + (size_t)wsel * CC * CC)[i] = o;
}

// ---------------- concat q/k/v biases into one f32[1536] ----------------
__global__ __launch_bounds__(256) void biascat_kernel(const float* __restrict__ bq,
                                                      const float* __restrict__ bk,
                                                      const float* __restrict__ bv,
                                                      float* __restrict__ bcat) {
    int i = blockIdx.x * 256 + threadIdx.x;
    if (i >= 3 * CC) return;
    float v = (i < CC) ? bq[i] : (i < 2 * CC ? bk[i - CC] : bv[i - 2 * CC]);
    bcat[i] = v;
}

// ---------------- GroupNorm stats: one block per (group, batch) ----------------
__global__ __launch_bounds__(256) void gn_stats_kernel(const float* __restrict__ x,
                                                       float2* __restrict__ stats) {
    int g = blockIdx.x, b = blockIdx.y, t = threadIdx.x;
    const float4* xp = reinterpret_cast<const float4*>(x + ((size_t)b * CC + (size_t)g * CPG) * LL);
    float s = 0.f, ss = 0.f;
    for (int it = 0; it < 64; ++it) {
        float4 v = xp[it * 256 + t];
        s += v.x + v.y + v.z + v.w;
        ss += v.x * v.x + v.y * v.y + v.z * v.z + v.w * v.w;
    }
    #pragma unroll
    for (int off = 32; off; off >>= 1) { s += __shfl_xor(s, off, 64); ss += __shfl_xor(ss, off, 64); }
    __shared__ float rs[4], rss[4];
    int wave = t >> 6, lane = t & 63;
    if (lane == 0) { rs[wave] = s; rss[wave] = ss; }
    __syncthreads();
    if (t == 0) {
        float S = rs[0] + rs[1] + rs[2] + rs[3];
        float SS = rss[0] + rss[1] + rss[2] + rss[3];
        float mean = S * (1.f / 65536.f);
        float var = SS * (1.f / 65536.f) - mean * mean;
        var = fmaxf(var, 0.f);
        stats[b * NG + g] = make_float2(mean, rsqrtf(var + EPSV));
    }
}

// -------- GroupNorm normalize + transpose: x[b][c][l] f32 -> hT[b][l][c] bf16 --------
__global__ __launch_bounds__(256) void gn_norm_t_kernel(const float* __restrict__ x,
                                                        const float2* __restrict__ stats,
                                                        const float* __restrict__ gsc,
                                                        const float* __restrict__ gbi,
                                                        u16* __restrict__ hT) {
    int lt = blockIdx.x, ct = blockIdx.y, b = blockIdx.z;
    __shared__ u16 tile[64][72];
    int t = threadIdx.x;
    int cl0 = t >> 4, c4 = (t & 15) * 4;
    #pragma unroll
    for (int p = 0; p < 4; ++p) {
        int cl = p * 16 + cl0;
        int cg = ct * 64 + cl;
        float2 st = stats[b * NG + (cg >> 4)];
        float sc = gsc[cg] * st.y;
        float bi = gbi[cg];
        float4 v = *reinterpret_cast<const float4*>(x + ((size_t)b * CC + cg) * LL + lt * 64 + c4);
        tile[cl][c4 + 0] = f2bf((v.x - st.x) * sc + bi);
        tile[cl][c4 + 1] = f2bf((v.y - st.x) * sc + bi);
        tile[cl][c4 + 2] = f2bf((v.z - st.x) * sc + bi);
        tile[cl][c4 + 3] = f2bf((v.w - st.x) * sc + bi);
    }
    __syncthreads();
    int r = t >> 3, c8 = (t & 7) * 8;
    #pragma unroll
    for (int p = 0; p < 2; ++p) {
        int ll = p * 32 + r;
        s16x8 ov;
        #pragma unroll
        for (int j = 0; j < 8; ++j) ov[j] = (short)tile[c8 + j][ll];
        u16* hp = hT + ((size_t)b * LL + lt * 64 + ll) * CC + ct * 64 + c8;
        *reinterpret_cast<s16x8*>(hp) = ov;
    }
}

// ---------------- generic GEMM: Out = f(A * B^T * scale) + bias ----------------
// mode 0: fused QKV. blocks nt/4==0 -> Out (qT), ==1 -> OutK (kT),
//         ==2 -> OutV stored TRANSPOSED as [c][l] (vv). B spans 1536 rows of wbf.
// mode 1: exp epilogue + atomic rowsum (attention S pass), Nout=4096.
// mode 2: multiply rows by 1/rowsum (attention PV pass).
// mode 3: proj: + bias then TRANSPOSED f32 store with residual: fout = xres + val.
// Pipelined K-loop: 3 LDS buffers, prefetch distance 2, raw s_barrier + vmcnt(8/4/0).
__global__ __launch_bounds__(256) void gemm_kernel(const u16* __restrict__ A, size_t asb, int lda,
                                                   const u16* __restrict__ B, size_t bsb, int ldb,
                                                   const float* __restrict__ bias, float scale,
                                                   u16* __restrict__ Out, u16* __restrict__ OutK,
                                                   u16* __restrict__ OutV, size_t osb,
                                                   const float* __restrict__ xres,
                                                   float* __restrict__ fout,
                                                   int Nout, int K, int mode,
                                                   float* __restrict__ rsum) {
    // pool: 3 x (As 8KB + Bs 8KB) = 48 KB; epilogue reuses [0, 128*136) u16
    __shared__ u16 pool[24576];
    u16* Asb = pool;             // 3 bufs of 4096 u16
    u16* Bsb = pool + 12288;     // 3 bufs of 4096 u16
    int mt = blockIdx.x, nt = blockIdx.y, b = blockIdx.z;
    int t = threadIdx.x;
    int wave = t >> 6, lane = t & 63;
    int wm = (wave >> 1) * 64, wn = (wave & 1) * 64;
    int l15 = lane & 15, quad = lane >> 4;
    f32x4 acc[4][4] = {};
    const u16* Ab = A + (size_t)b * asb + (size_t)mt * 128 * lda;
    const u16* Bb = B + (size_t)b * bsb + (size_t)nt * 128 * ldb;
    // Staging: LDS slot s (16B) holds global (row = s>>2, chunk = (s&3)^((s>>2)&3)^((s>>4)&3)).
    int swzg = ((lane & 3) ^ ((lane >> 2) & 3) ^ ((lane >> 4) & 3)) * 8;
    int row0 = wave * 16 + (lane >> 2);
    int row1 = 64 + row0;
    const u16* Ap0 = Ab + (size_t)row0 * lda + swzg;
    const u16* Ap1 = Ab + (size_t)row1 * lda + swzg;
    const u16* Bp0 = Bb + (size_t)row0 * ldb + swzg;
    const u16* Bp1 = Bb + (size_t)row1 * ldb + swzg;
    int wo = wave * 512;
    // Fragment read swizzle (round-4 derivation)
    int swzf = (l15 & 3) ^ (l15 >> 2);
    int aoff = (wm + l15) * 32 + ((quad ^ swzf) * 8);
    int boff = (wn + l15) * 32 + ((quad ^ swzf) * 8);
    const int iters = K >> 5;
    // prologue: chunk 0 -> buf0, chunk 1 -> buf1 (8 loads in flight)
    gload16(Ap0, Asb + wo);                 gload16(Ap1, Asb + 2048 + wo);
    gload16(Bp0, Bsb + wo);                 gload16(Bp1, Bsb + 2048 + wo);
    gload16(Ap0 + 32, Asb + 4096 + wo);     gload16(Ap1 + 32, Asb + 4096 + 2048 + wo);
    gload16(Bp0 + 32, Bsb + 4096 + wo);     gload16(Bp1 + 32, Bsb + 4096 + 2048 + wo);
    int cur = 0;
    for (int i = 0; i < iters; ++i) {
        if (i + 2 < iters) {
            int pf = cur + 2; if (pf >= 3) pf -= 3;
            int kk = (i + 2) * 32;
            u16* as = Asb + pf * 4096; u16* bs = Bsb + pf * 4096;
            gload16(Ap0 + kk, as + wo);        gload16(Ap1 + kk, as + 2048 + wo);
            gload16(Bp0 + kk, bs + wo);        gload16(Bp1 + kk, bs + 2048 + wo);
            ASM_WAITV(8);      // chunk i's 4 loads retired; 8 newer stay in flight
        } else if (i + 1 < iters) {
            ASM_WAITV(4);
        } else {
            ASM_WAITV(0);
        }
        ASM_SBAR();            // all waves' chunk-i loads landed
        const u16* As = Asb + cur * 4096;
        const u16* Bs = Bsb + cur * 4096;
        bf8v af[4], bfr[4];
        #pragma unroll
        for (int ii = 0; ii < 4; ++ii)
            af[ii] = ld_bf8(&As[aoff + ii * 512]);
        #pragma unroll
        for (int j = 0; j < 4; ++j)
            bfr[j] = ld_bf8(&Bs[boff + j * 512]);
        #pragma unroll
        for (int ii = 0; ii < 4; ++ii)
            #pragma unroll
            for (int j = 0; j < 4; ++j)
                acc[ii][j] = __builtin_amdgcn_mfma_f32_16x16x32_bf16(af[ii], bfr[j], acc[ii][j], 0, 0, 0);
        ASM_SBAR();            // reads of buf cur done before it is refilled
        cur = (cur == 2) ? 0 : cur + 1;
    }
    // ---- epilogue: acc -> bf16 LDS tile (stride 136) -> coalesced stores ----
    __syncthreads();
    int nt_sel = (mode == 0) ? (nt >> 2) : 0;
    int ntl = (mode == 0) ? (nt & 3) : nt;
    bool transT = (mode == 3) || (mode == 0 && nt_sel == 2);
    float invl[4][4];
    if (mode == 2) {
        #pragma unroll
        for (int i = 0; i < 4; ++i)
            #pragma unroll
            for (int r = 0; r < 4; ++r)
                invl[i][r] = 1.f / rsum[(size_t)b * LL + mt * 128 + wm + i * 16 + quad * 4 + r];
    }
    #pragma unroll
    for (int j = 0; j < 4; ++j) {
        float bv = bias ? bias[nt * 128 + wn + j * 16 + l15] : 0.f;
        #pragma unroll
        for (int i = 0; i < 4; ++i) {
            #pragma unroll
            for (int r = 0; r < 4; ++r) {
                int row = wm + i * 16 + quad * 4 + r;
                int col = wn + j * 16 + l15;
                float val = acc[i][j][r] * scale;
                if (mode == 1) val = __expf(val);
                if (mode == 2) val *= invl[i][r];
                val += bv;
                if (transT) pool[col * 136 + row] = f2bf(val);
                else        pool[row * 136 + col] = f2bf(val);
            }
        }
    }
    __syncthreads();
    if (mode == 3) {
        // residual + f32 transposed store: fout[b][c][l] = xres + tile^T
        const float* xb = xres + ((size_t)b * CC + nt * 128) * LL + mt * 128;
        float* ob = fout + ((size_t)b * CC + nt * 128) * LL + mt * 128;
        #pragma unroll
        for (int it = 0; it < 16; ++it) {
            int idx = it * 256 + t;
            int cl = idx >> 5, ch = (idx & 31) * 4;
            short4 pv = *reinterpret_cast<const short4*>(&pool[cl * 136 + ch]);
            float4 xv = *reinterpret_cast<const float4*>(xb + (size_t)cl * LL + ch);
            float4 ov;
            ov.x = xv.x + bf2f((u16)pv.x);
            ov.y = xv.y + bf2f((u16)pv.y);
            ov.z = xv.z + bf2f((u16)pv.z);
            ov.w = xv.w + bf2f((u16)pv.w);
            *reinterpret_cast<float4*>(ob + (size_t)cl * LL + ch) = ov;
        }
    } else if (transT) {
        // V of fused QKV: bf16 transposed store into vv[b][c][l]
        u16* Ob = OutV + (size_t)b * osb + (size_t)(ntl * 128) * LL + mt * 128;
        #pragma unroll
        for (int it = 0; it < 8; ++it) {
            int idx = it * 256 + t;
            int cl = idx >> 4, ch = (idx & 15) * 8;
            s16x8 val = *reinterpret_cast<const s16x8*>(&pool[cl * 136 + ch]);
            *reinterpret_cast<s16x8*>(Ob + (size_t)cl * LL + ch) = val;
        }
    } else {
        u16* base = (mode == 0 && nt_sel == 1) ? OutK : Out;
        u16* Ob = base + (size_t)b * osb + (size_t)(mt * 128) * Nout + ntl * 128;
        #pragma unroll
        for (int it = 0; it < 8; ++it) {
            int idx = it * 256 + t;
            int row = idx >> 4, ch = (idx & 15) * 8;
            s16x8 val = *reinterpret_cast<const s16x8*>(&pool[row * 136 + ch]);
            *reinterpret_cast<s16x8*>(Ob + (size_t)row * Nout + ch) = val;
            if (mode == 1) {
                float part = 0.f;
                #pragma unroll
                for (int j = 0; j < 8; ++j) part += bf2f((u16)val[j]);
                part += __shfl_xor(part, 1, 64);
                part += __shfl_xor(part, 2, 64);
                part += __shfl_xor(part, 4, 64);
                part += __shfl_xor(part, 8, 64);
                if ((t & 15) == 0)
                    atomicAdd(rsum + (size_t)b * LL + mt * 128 + row, part);
            }
        }
    }
}

// ------------------------- flash attention (FALLBACK path only) -------------------------
__global__ __launch_bounds__(256) void attn_kernel(const u16* __restrict__ qT,
                                                   const u16* __restrict__ kT,
                                                   const u16* __restrict__ v,
                                                   u16* __restrict__ h2T) {
    const int D = CC;
    int b = blockIdx.y;
    int i0 = blockIdx.x * 32;
    int t = threadIdx.x;
    int wave = t >> 6, lane = t & 63;
    int l15 = lane & 15, quad = lane >> 4;
    int ih = wave >> 1, jh = wave & 1;
    int cb = jh * 256;

    __shared__ float SL[32 * 68];
    __shared__ u16 PL[32 * 72];
    __shared__ float mL[32], lL[32], aL[32];

    if (t < 32) { mL[t] = -1e30f; lL[t] = 0.f; }

    f32x4 opv[16] = {};
    const u16* qb = qT + ((size_t)b * LL + i0 + ih * 16 + l15) * D + quad * 8;
    const u16* kb = kT + (size_t)b * LL * D;
    const u16* vb = v + (size_t)b * D * LL;
    const float scale = 0.044194173824159216f;
    __syncthreads();

    for (int j0 = 0; j0 < LL; j0 += 64) {
        f32x4 sacc0 = {}, sacc1 = {};
        const u16* kp0 = kb + ((size_t)(j0 + jh * 32 + l15)) * D + quad * 8;
        const u16* kp1 = kp0 + (size_t)16 * D;
        #pragma unroll
        for (int kc = 0; kc < 16; ++kc) {
            bf8v a = ld_bf8(qb + kc * 32);
            bf8v b0 = ld_bf8(kp0 + kc * 32);
            bf8v b1 = ld_bf8(kp1 + kc * 32);
            sacc0 = __builtin_amdgcn_mfma_f32_16x16x32_bf16(a, b0, sacc0, 0, 0, 0);
            sacc1 = __builtin_amdgcn_mfma_f32_16x16x32_bf16(a, b1, sacc1, 0, 0, 0);
        }
        #pragma unroll
        for (int r = 0; r < 4; ++r) {
            SL[(ih * 16 + quad * 4 + r) * 68 + jh * 32 + l15] = sacc0[r] * scale;
            SL[(ih * 16 + quad * 4 + r) * 68 + jh * 32 + 16 + l15] = sacc1[r] * scale;
        }
        __syncthreads();
        {
            int row = t >> 3, c8 = (t & 7) * 8;
            float4 s0 = *reinterpret_cast<const float4*>(&SL[row * 68 + c8]);
            float4 s1 = *reinterpret_cast<const float4*>(&SL[row * 68 + c8 + 4]);
            float sv[8] = { s0.x, s0.y, s0.z, s0.w, s1.x, s1.y, s1.z, s1.w };
            float mx = sv[0];
            #pragma unroll
            for (int j = 1; j < 8; ++j) mx = fmaxf(mx, sv[j]);
            #pragma unroll
            for (int off = 1; off < 8; off <<= 1) mx = fmaxf(mx, __shfl_xor(mx, off, 64));
            float mold = mL[row];
            float mnew = fmaxf(mold, mx);
            float alpha = __expf(mold - mnew);
            float s = 0.f;
            #pragma unroll
            for (int j = 0; j < 8; ++j) { float pp = __expf(sv[j] - mnew); sv[j] = pp; s += pp; }
            #pragma unroll
            for (int off = 1; off < 8; off <<= 1) s += __shfl_xor(s, off, 64);
            ushort4 p0, p1;
            p0.x = f2bf(sv[0]); p0.y = f2bf(sv[1]); p0.z = f2bf(sv[2]); p0.w = f2bf(sv[3]);
            p1.x = f2bf(sv[4]); p1.y = f2bf(sv[5]); p1.z = f2bf(sv[6]); p1.w = f2bf(sv[7]);
            *reinterpret_cast<ushort4*>(&PL[row * 72 + c8]) = p0;
            *reinterpret_cast<ushort4*>(&PL[row * 72 + c8 + 4]) = p1;
            if ((t & 7) == 0) {
                lL[row] = lL[row] * alpha + s;
                mL[row] = mnew;
                aL[row] = alpha;
            }
        }
        __syncthreads();
        float al[4];
        #pragma unroll
        for (int r = 0; r < 4; ++r) al[r] = aL[ih * 16 + quad * 4 + r];
        #pragma unroll
        for (int nt2 = 0; nt2 < 16; ++nt2)
            #pragma unroll
            for (int r = 0; r < 4; ++r) opv[nt2][r] *= al[r];
        #pragma unroll
        for (int kk = 0; kk < 2; ++kk) {
            bf8v pa = ld_bf8(&PL[(ih * 16 + l15) * 72 + kk * 32 + quad * 8]);
            #pragma unroll
            for (int nt2 = 0; nt2 < 16; ++nt2) {
                const u16* vp = vb + (size_t)(cb + nt2 * 16 + l15) * LL + j0 + kk * 32 + quad * 8;
                bf8v bv = ld_bf8(vp);
                opv[nt2] = __builtin_amdgcn_mfma_f32_16x16x32_bf16(pa, bv, opv[nt2], 0, 0, 0);
            }
        }
        __syncthreads();
    }
    float il[4];
    #pragma unroll
    for (int r = 0; r < 4; ++r) il[r] = 1.f / lL[ih * 16 + quad * 4 + r];
    #pragma unroll
    for (int nt2 = 0; nt2 < 16; ++nt2) {
        #pragma unroll
        for (int r = 0; r < 4; ++r) {
            int irow = ih * 16 + quad * 4 + r;
            h2T[((size_t)b * LL + i0 + irow) * D + cb + nt2 * 16 + l15] = f2bf(opv[nt2][r] * il[r]);
        }
    }
}

extern "C" void kernel_launch(void* const* d_in, const int* in_sizes, int n_in,
                              void* d_out, int out_size, void* d_ws, size_t ws_size,
                              hipStream_t stream) {
    const float* x   = (const float*)d_in[0];
    const float* gsc = (const float*)d_in[1];
    const float* gbi = (const float*)d_in[2];
    const float* wq  = (const float*)d_in[3];
    const float* bq  = (const float*)d_in[4];
    const float* wk  = (const float*)d_in[5];
    const float* bk  = (const float*)d_in[6];
    const float* wv  = (const float*)d_in[7];
    const float* bv  = (const float*)d_in[8];
    const float* wp  = (const float*)d_in[9];
    const float* bp  = (const float*)d_in[10];
    float* out = (float*)d_out;

    char* ws = (char*)d_ws;
    const size_t SZ   = (size_t)BB * LL * CC * 2;     // 16 MiB per [b][l][c] bf16 buffer
    const size_t WQSZ = (size_t)4 * CC * CC * 2;      // 2 MiB bf16 weights (q,k,v,p rows)
    const size_t SSZ  = (size_t)BB * LL * LL * 2;     // 128 MiB bf16 scores (all batches)
    const size_t RSZ  = (size_t)BB * LL * 4;          // 64 KiB f32 rowsums
    u16* bufA = (u16*)(ws);                  // hT -> h2T
    u16* bufB = (u16*)(ws + SZ);             // qT
    u16* bufC = (u16*)(ws + 2 * SZ);         // kT
    u16* bufD = (u16*)(ws + 3 * SZ);         // vv ([b][c][l])
    u16* wbf  = (u16*)(ws + 4 * SZ);
    float2* stats = (float2*)(ws + 4 * SZ + WQSZ);
    float* bcat   = (float*)(ws + 4 * SZ + WQSZ + 4096);
    float* rowsum = (float*)(ws + 4 * SZ + WQSZ + 4096 + 8192);
    u16* Sbuf = (u16*)(ws + 4 * SZ + WQSZ + 4096 + 8192 + RSZ);
    const size_t NEEDED = 4 * SZ + WQSZ + 4096 + 8192 + RSZ + SSZ;
    const float scale = 0.044194173824159216f;        // 512^-0.5
    const size_t BLC = (size_t)LL * CC;

    wconv_kernel<<<dim3(256, 4), 256, 0, stream>>>(wq, wk, wv, wp, wbf);
    biascat_kernel<<<dim3(6), 256, 0, stream>>>(bq, bk, bv, bcat);
    gn_stats_kernel<<<dim3(NG, BB), 256, 0, stream>>>(x, stats);
    gn_norm_t_kernel<<<dim3(64, 8, BB), 256, 0, stream>>>(x, stats, gsc, gbi, bufA);
    // fused QKV: nt 0-3 -> qT(bufB), 4-7 -> kT(bufC), 8-11 -> vv(bufD, transposed)
    gemm_kernel<<<dim3(32, 12, BB), 256, 0, stream>>>(bufA, BLC, CC, wbf, 0, CC, bcat, 1.f,
                                                      bufB, bufC, bufD, BLC, nullptr, nullptr,
                                                      CC, CC, 0, nullptr);
    if (ws_size >= NEEDED) {
        // Two-pass attention, softmax fused into GEMM epilogues:
        //   P' = exp(QK^T*scale) with atomic rowsums; O = (P' V) / rowsum
        zero_kernel<<<dim3((BB * LL + 255) / 256), 256, 0, stream>>>(rowsum, BB * LL);
        gemm_kernel<<<dim3(32, 32, BB), 256, 0, stream>>>(bufB, BLC, CC, bufC, BLC, CC,
                                                          nullptr, scale, Sbuf, nullptr, nullptr,
                                                          (size_t)LL * LL, nullptr, nullptr,
                                                          LL, CC, 1, rowsum);
        gemm_kernel<<<dim3(32, 4, BB), 256, 0, stream>>>(Sbuf, (size_t)LL * LL, LL, bufD, BLC, LL,
                                                         nullptr, 1.f, bufA, nullptr, nullptr,
                                                         BLC, nullptr, nullptr,
                                                         CC, LL, 2, rowsum);
    } else {
        // Fallback: flash attention
        attn_kernel<<<dim3(LL / 32, BB), 256, 0, stream>>>(bufB, bufC, bufD, bufA);
    }
    // proj + residual + transposed f32 store (replaces proj GEMM + final kernel)
    gemm_kernel<<<dim3(32, 4, BB), 256, 0, stream>>>(bufA, BLC, CC, wbf + 3 * CC * CC, 0, CC,
                                                     bp, 1.f, nullptr, nullptr, nullptr,
                                                     0, x, out, CC, CC, 3, nullptr);
}

// Round 7
// 363.727 us; speedup vs baseline: 1.1034x; 1.1034x over previous
//
#include <hip/hip_runtime.h>
#include <math.h>

// Shapes (fixed by the problem): b=4, c=512, l=4096, 32 groups.
// Inputs/outputs are float32; internal compute path is bf16 MFMA.
#define BB 4
#define CC 512
#define LL 4096
#define NG 32
#define CPG 16
#define EPSV 1e-6f

typedef short s16x8 __attribute__((ext_vector_type(8)));
typedef __bf16 bf8v __attribute__((ext_vector_type(8)));
typedef float f32x4 __attribute__((ext_vector_type(4)));
typedef unsigned short u16;

typedef const __attribute__((address_space(1))) void g1_void;
typedef __attribute__((address_space(3))) void l3_void;

// raw barrier / waitcnt (memory clobber = compiler reorder fence, no vmcnt drain)
#define ASM_SBAR() asm volatile("s_barrier" ::: "memory")
#define ASM_WAITV(N) asm volatile("s_waitcnt vmcnt(" #N ")" ::: "memory")

static __device__ __forceinline__ float bf2f(u16 h) {
    unsigned int u = ((unsigned int)h) << 16;
    union { unsigned int u; float f; } c; c.u = u; return c.f;
}
static __device__ __forceinline__ u16 f2bf(float f) {
    union { float f; unsigned int u; } c; c.f = f;
    unsigned int lsb = (c.u >> 16) & 1u;
    c.u += 0x7fffu + lsb;           // round-to-nearest-even
    return (u16)(c.u >> 16);
}
static __device__ __forceinline__ bf8v ld_bf8(const u16* p) {
    return *reinterpret_cast<const bf8v*>(p);
}
// async global->LDS; HW writes lds_base + lane*16 (wave-uniform base required)
static __device__ __forceinline__ void gload16(const u16* g, u16* l) {
    __builtin_amdgcn_global_load_lds((g1_void*)g, (l3_void*)l, 16, 0, 0);
}

// ---------------- zero rowsum buffer ----------------
__global__ __launch_bounds__(256) void zero_kernel(float* __restrict__ p, int n) {
    int i = blockIdx.x * 256 + threadIdx.x;
    if (i < n) p[i] = 0.f;
}

// ---------------- weight convert: four 512x512 f32 -> bf16 (rows: q,k,v,p) ----------------
__global__ __launch_bounds__(256) void wconv_kernel(const float* __restrict__ w0,
                                                    const float* __restrict__ w1,
                                                    const float* __restrict__ w2,
                                                    const float* __restrict__ w3,
                                                    u16* __restrict__ wbf) {
    int i = blockIdx.x * 256 + threadIdx.x;      // 0..65535 float4 chunks
    int wsel = blockIdx.y;
    const float* src = (wsel == 0) ? w0 : (wsel == 1) ? w1 : (wsel == 2) ? w2 : w3;
    float4 v = reinterpret_cast<const float4*>(src)[i];
    ushort4 o;
    o.x = f2bf(v.x); o.y = f2bf(v.y); o.z = f2bf(v.z); o.w = f2bf(v.w);
    reinterpret_cast<ushort4*>(wbf + (size_t)wsel * CC * CC)[i] = o;
}

// ---------------- concat q/k/v biases into one f32[1536] ----------------
__global__ __launch_bounds__(256) void biascat_kernel(const float* __restrict__ bq,
                                                      const float* __restrict__ bk,
                                                      const float* __restrict__ bv,
                                                      float* __restrict__ bcat) {
    int i = blockIdx.x * 256 + threadIdx.x;
    if (i >= 3 * CC) return;
    float v = (i < CC) ? bq[i] : (i < 2 * CC ? bk[i - CC] : bv[i - 2 * CC]);
    bcat[i] = v;
}

// ---------------- GroupNorm stats: one block per (group, batch) ----------------
__global__ __launch_bounds__(256) void gn_stats_kernel(const float* __restrict__ x,
                                                       float2* __restrict__ stats) {
    int g = blockIdx.x, b = blockIdx.y, t = threadIdx.x;
    const float4* xp = reinterpret_cast<const float4*>(x + ((size_t)b * CC + (size_t)g * CPG) * LL);
    float s = 0.f, ss = 0.f;
    for (int it = 0; it < 64; ++it) {
        float4 v = xp[it * 256 + t];
        s += v.x + v.y + v.z + v.w;
        ss += v.x * v.x + v.y * v.y + v.z * v.z + v.w * v.w;
    }
    #pragma unroll
    for (int off = 32; off; off >>= 1) { s += __shfl_xor(s, off, 64); ss += __shfl_xor(ss, off, 64); }
    __shared__ float rs[4], rss[4];
    int wave = t >> 6, lane = t & 63;
    if (lane == 0) { rs[wave] = s; rss[wave] = ss; }
    __syncthreads();
    if (t == 0) {
        float S = rs[0] + rs[1] + rs[2] + rs[3];
        float SS = rss[0] + rss[1] + rss[2] + rss[3];
        float mean = S * (1.f / 65536.f);
        float var = SS * (1.f / 65536.f) - mean * mean;
        var = fmaxf(var, 0.f);
        stats[b * NG + g] = make_float2(mean, rsqrtf(var + EPSV));
    }
}

// -------- GroupNorm normalize + transpose: x[b][c][l] f32 -> hT[b][l][c] bf16 --------
__global__ __launch_bounds__(256) void gn_norm_t_kernel(const float* __restrict__ x,
                                                        const float2* __restrict__ stats,
                                                        const float* __restrict__ gsc,
                                                        const float* __restrict__ gbi,
                                                        u16* __restrict__ hT) {
    int lt = blockIdx.x, ct = blockIdx.y, b = blockIdx.z;
    __shared__ u16 tile[64][72];
    int t = threadIdx.x;
    int cl0 = t >> 4, c4 = (t & 15) * 4;
    #pragma unroll
    for (int p = 0; p < 4; ++p) {
        int cl = p * 16 + cl0;
        int cg = ct * 64 + cl;
        float2 st = stats[b * NG + (cg >> 4)];
        float sc = gsc[cg] * st.y;
        float bi = gbi[cg];
        float4 v = *reinterpret_cast<const float4*>(x + ((size_t)b * CC + cg) * LL + lt * 64 + c4);
        tile[cl][c4 + 0] = f2bf((v.x - st.x) * sc + bi);
        tile[cl][c4 + 1] = f2bf((v.y - st.x) * sc + bi);
        tile[cl][c4 + 2] = f2bf((v.z - st.x) * sc + bi);
        tile[cl][c4 + 3] = f2bf((v.w - st.x) * sc + bi);
    }
    __syncthreads();
    int r = t >> 3, c8 = (t & 7) * 8;
    #pragma unroll
    for (int p = 0; p < 2; ++p) {
        int ll = p * 32 + r;
        s16x8 ov;
        #pragma unroll
        for (int j = 0; j < 8; ++j) ov[j] = (short)tile[c8 + j][ll];
        u16* hp = hT + ((size_t)b * LL + lt * 64 + ll) * CC + ct * 64 + c8;
        *reinterpret_cast<s16x8*>(hp) = ov;
    }
}

// ---------------- generic GEMM: Out = f(A * B^T * scale) + bias ----------------
// MODE 0: fused QKV. nt/4==0 -> Out (qT), ==1 -> OutK (kT), ==2 -> OutV transposed [c][l].
// MODE 1: exp epilogue + atomic rowsum (attention S pass), Nout=4096.
// MODE 2: multiply rows by 1/rowsum (attention PV pass).
// MODE 3: proj: + bias, TRANSPOSED f32 store with residual: fout = xres + val.
// Pipelined K-loop: 2 LDS buffers, prefetch distance 2 (issued after 2nd barrier into
// the just-consumed buffer), raw s_barrier + vmcnt(4)/vmcnt(0) — no mid-loop drain.
// LDS = 34816 B -> 4 blocks/CU.
template <int MODE>
__global__ __launch_bounds__(256) void gemm_kernel(const u16* __restrict__ A, size_t asb, int lda,
                                                   const u16* __restrict__ B, size_t bsb, int ldb,
                                                   const float* __restrict__ bias, float scale,
                                                   u16* __restrict__ Out, u16* __restrict__ OutK,
                                                   u16* __restrict__ OutV, size_t osb,
                                                   const float* __restrict__ xres,
                                                   float* __restrict__ fout,
                                                   int Nout, int K,
                                                   float* __restrict__ rsum) {
    // pool: staging = 2 x (As 8KB + Bs 8KB) = 32 KB; epilogue tile 128*136*2 = 34816 B
    __shared__ u16 pool[17408];
    int mt = blockIdx.x, nt = blockIdx.y, b = blockIdx.z;
    int t = threadIdx.x;
    int wave = t >> 6, lane = t & 63;
    int wm = (wave >> 1) * 64, wn = (wave & 1) * 64;
    int l15 = lane & 15, quad = lane >> 4;
    f32x4 acc[4][4] = {};
    const u16* Ab = A + (size_t)b * asb + (size_t)mt * 128 * lda;
    const u16* Bb = B + (size_t)b * bsb + (size_t)nt * 128 * ldb;
    // Staging: LDS slot s (16B) holds global (row = s>>2, chunk = (s&3)^((s>>2)&3)^((s>>4)&3)).
    int swzg = ((lane & 3) ^ ((lane >> 2) & 3) ^ ((lane >> 4) & 3)) * 8;
    int row0 = wave * 16 + (lane >> 2);
    int row1 = 64 + row0;
    const u16* Ap0 = Ab + (size_t)row0 * lda + swzg;
    const u16* Ap1 = Ab + (size_t)row1 * lda + swzg;
    const u16* Bp0 = Bb + (size_t)row0 * ldb + swzg;
    const u16* Bp1 = Bb + (size_t)row1 * ldb + swzg;
    int wo = wave * 512;
    // Fragment read swizzle (round-4 derivation)
    int swzf = (l15 & 3) ^ (l15 >> 2);
    int aoff = (wm + l15) * 32 + ((quad ^ swzf) * 8);
    int boff = (wn + l15) * 32 + ((quad ^ swzf) * 8);
    const int iters = K >> 5;
    // buffers: A: pool[0],pool[4096); B: pool[8192),pool[12288)
    // prologue: chunk 0 -> buf0, chunk 1 -> buf1 (8 loads in flight / wave)
    gload16(Ap0, pool + wo);                gload16(Ap1, pool + 2048 + wo);
    gload16(Bp0, pool + 8192 + wo);         gload16(Bp1, pool + 8192 + 2048 + wo);
    gload16(Ap0 + 32, pool + 4096 + wo);    gload16(Ap1 + 32, pool + 4096 + 2048 + wo);
    gload16(Bp0 + 32, pool + 12288 + wo);   gload16(Bp1 + 32, pool + 12288 + 2048 + wo);
    for (int i = 0; i < iters; ++i) {
        if (i + 1 < iters) { ASM_WAITV(4); } else { ASM_WAITV(0); }
        ASM_SBAR();            // all waves' chunk-i loads landed
        int bs = (i & 1) * 4096;
        const u16* As = pool + bs;
        const u16* Bs = pool + 8192 + bs;
        bf8v af[4], bfr[4];
        #pragma unroll
        for (int ii = 0; ii < 4; ++ii)
            af[ii] = ld_bf8(&As[aoff + ii * 512]);
        #pragma unroll
        for (int j = 0; j < 4; ++j)
            bfr[j] = ld_bf8(&Bs[boff + j * 512]);
        #pragma unroll
        for (int ii = 0; ii < 4; ++ii)
            #pragma unroll
            for (int j = 0; j < 4; ++j)
                acc[ii][j] = __builtin_amdgcn_mfma_f32_16x16x32_bf16(af[ii], bfr[j], acc[ii][j], 0, 0, 0);
        ASM_SBAR();            // reads of buf (i&1) done before it is refilled below
        if (i + 2 < iters) {
            int kk = (i + 2) * 32;
            u16* as = pool + bs; u16* bsp = pool + 8192 + bs;
            gload16(Ap0 + kk, as + wo);        gload16(Ap1 + kk, as + 2048 + wo);
            gload16(Bp0 + kk, bsp + wo);       gload16(Bp1 + kk, bsp + 2048 + wo);
        }
    }
    // ---- epilogue: acc -> bf16 LDS tile (stride 136) -> coalesced stores ----
    __syncthreads();
    if (MODE == 1) {
        #pragma unroll
        for (int j = 0; j < 4; ++j)
            #pragma unroll
            for (int i = 0; i < 4; ++i)
                #pragma unroll
                for (int r = 0; r < 4; ++r) {
                    int row = wm + i * 16 + quad * 4 + r;
                    int col = wn + j * 16 + l15;
                    pool[row * 136 + col] = f2bf(__expf(acc[i][j][r] * scale));
                }
    } else if (MODE == 2) {
        float invl[4][4];
        #pragma unroll
        for (int i = 0; i < 4; ++i)
            #pragma unroll
            for (int r = 0; r < 4; ++r)
                invl[i][r] = 1.f / rsum[(size_t)b * LL + mt * 128 + wm + i * 16 + quad * 4 + r];
        #pragma unroll
        for (int j = 0; j < 4; ++j)
            #pragma unroll
            for (int i = 0; i < 4; ++i)
                #pragma unroll
                for (int r = 0; r < 4; ++r) {
                    int row = wm + i * 16 + quad * 4 + r;
                    int col = wn + j * 16 + l15;
                    pool[row * 136 + col] = f2bf(acc[i][j][r] * invl[i][r]);
                }
    } else {
        int nt_sel = (MODE == 0) ? (nt >> 2) : 0;
        bool transT = (MODE == 3) || (MODE == 0 && nt_sel == 2);
        #pragma unroll
        for (int j = 0; j < 4; ++j) {
            float bv = bias ? bias[nt * 128 + wn + j * 16 + l15] : 0.f;
            #pragma unroll
            for (int i = 0; i < 4; ++i)
                #pragma unroll
                for (int r = 0; r < 4; ++r) {
                    int row = wm + i * 16 + quad * 4 + r;
                    int col = wn + j * 16 + l15;
                    float val = acc[i][j][r] + bv;
                    if (transT) pool[col * 136 + row] = f2bf(val);
                    else        pool[row * 136 + col] = f2bf(val);
                }
        }
    }
    __syncthreads();
    if (MODE == 3) {
        // residual + f32 transposed store: fout[b][c][l] = xres + tile^T
        const float* xb = xres + ((size_t)b * CC + nt * 128) * LL + mt * 128;
        float* ob = fout + ((size_t)b * CC + nt * 128) * LL + mt * 128;
        #pragma unroll
        for (int it = 0; it < 16; ++it) {
            int idx = it * 256 + t;
            int cl = idx >> 5, ch = (idx & 31) * 4;
            short4 pv = *reinterpret_cast<const short4*>(&pool[cl * 136 + ch]);
            float4 xv = *reinterpret_cast<const float4*>(xb + (size_t)cl * LL + ch);
            float4 ov;
            ov.x = xv.x + bf2f((u16)pv.x);
            ov.y = xv.y + bf2f((u16)pv.y);
            ov.z = xv.z + bf2f((u16)pv.z);
            ov.w = xv.w + bf2f((u16)pv.w);
            *reinterpret_cast<float4*>(ob + (size_t)cl * LL + ch) = ov;
        }
    } else if (MODE == 0 && (nt >> 2) == 2) {
        // V of fused QKV: bf16 transposed store into vv[b][c][l]
        u16* Ob = OutV + (size_t)b * osb + (size_t)((nt & 3) * 128) * LL + mt * 128;
        #pragma unroll
        for (int it = 0; it < 8; ++it) {
            int idx = it * 256 + t;
            int cl = idx >> 4, ch = (idx & 15) * 8;
            s16x8 val = *reinterpret_cast<const s16x8*>(&pool[cl * 136 + ch]);
            *reinterpret_cast<s16x8*>(Ob + (size_t)cl * LL + ch) = val;
        }
    } else {
        int ntl = (MODE == 0) ? (nt & 3) : nt;
        u16* base = (MODE == 0 && (nt >> 2) == 1) ? OutK : Out;
        u16* Ob = base + (size_t)b * osb + (size_t)(mt * 128) * Nout + ntl * 128;
        #pragma unroll
        for (int it = 0; it < 8; ++it) {
            int idx = it * 256 + t;
            int row = idx >> 4, ch = (idx & 15) * 8;
            s16x8 val = *reinterpret_cast<const s16x8*>(&pool[row * 136 + ch]);
            *reinterpret_cast<s16x8*>(Ob + (size_t)row * Nout + ch) = val;
            if (MODE == 1) {
                float part = 0.f;
                #pragma unroll
                for (int j = 0; j < 8; ++j) part += bf2f((u16)val[j]);
                part += __shfl_xor(part, 1, 64);
                part += __shfl_xor(part, 2, 64);
                part += __shfl_xor(part, 4, 64);
                part += __shfl_xor(part, 8, 64);
                if ((t & 15) == 0)
                    atomicAdd(rsum + (size_t)b * LL + mt * 128 + row, part);
            }
        }
    }
}

// ------------------------- flash attention (FALLBACK path only) -------------------------
__global__ __launch_bounds__(256) void attn_kernel(const u16* __restrict__ qT,
                                                   const u16* __restrict__ kT,
                                                   const u16* __restrict__ v,
                                                   u16* __restrict__ h2T) {
    const int D = CC;
    int b = blockIdx.y;
    int i0 = blockIdx.x * 32;
    int t = threadIdx.x;
    int wave = t >> 6, lane = t & 63;
    int l15 = lane & 15, quad = lane >> 4;
    int ih = wave >> 1, jh = wave & 1;
    int cb = jh * 256;

    __shared__ float SL[32 * 68];
    __shared__ u16 PL[32 * 72];
    __shared__ float mL[32], lL[32], aL[32];

    if (t < 32) { mL[t] = -1e30f; lL[t] = 0.f; }

    f32x4 opv[16] = {};
    const u16* qb = qT + ((size_t)b * LL + i0 + ih * 16 + l15) * D + quad * 8;
    const u16* kb = kT + (size_t)b * LL * D;
    const u16* vb = v + (size_t)b * D * LL;
    const float scale = 0.044194173824159216f;
    __syncthreads();

    for (int j0 = 0; j0 < LL; j0 += 64) {
        f32x4 sacc0 = {}, sacc1 = {};
        const u16* kp0 = kb + ((size_t)(j0 + jh * 32 + l15)) * D + quad * 8;
        const u16* kp1 = kp0 + (size_t)16 * D;
        #pragma unroll
        for (int kc = 0; kc < 16; ++kc) {
            bf8v a = ld_bf8(qb + kc * 32);
            bf8v b0 = ld_bf8(kp0 + kc * 32);
            bf8v b1 = ld_bf8(kp1 + kc * 32);
            sacc0 = __builtin_amdgcn_mfma_f32_16x16x32_bf16(a, b0, sacc0, 0, 0, 0);
            sacc1 = __builtin_amdgcn_mfma_f32_16x16x32_bf16(a, b1, sacc1, 0, 0, 0);
        }
        #pragma unroll
        for (int r = 0; r < 4; ++r) {
            SL[(ih * 16 + quad * 4 + r) * 68 + jh * 32 + l15] = sacc0[r] * scale;
            SL[(ih * 16 + quad * 4 + r) * 68 + jh * 32 + 16 + l15] = sacc1[r] * scale;
        }
        __syncthreads();
        {
            int row = t >> 3, c8 = (t & 7) * 8;
            float4 s0 = *reinterpret_cast<const float4*>(&SL[row * 68 + c8]);
            float4 s1 = *reinterpret_cast<const float4*>(&SL[row * 68 + c8 + 4]);
            float sv[8] = { s0.x, s0.y, s0.z, s0.w, s1.x, s1.y, s1.z, s1.w };
            float mx = sv[0];
            #pragma unroll
            for (int j = 1; j < 8; ++j) mx = fmaxf(mx, sv[j]);
            #pragma unroll
            for (int off = 1; off < 8; off <<= 1) mx = fmaxf(mx, __shfl_xor(mx, off, 64));
            float mold = mL[row];
            float mnew = fmaxf(mold, mx);
            float alpha = __expf(mold - mnew);
            float s = 0.f;
            #pragma unroll
            for (int j = 0; j < 8; ++j) { float pp = __expf(sv[j] - mnew); sv[j] = pp; s += pp; }
            #pragma unroll
            for (int off = 1; off < 8; off <<= 1) s += __shfl_xor(s, off, 64);
            ushort4 p0, p1;
            p0.x = f2bf(sv[0]); p0.y = f2bf(sv[1]); p0.z = f2bf(sv[2]); p0.w = f2bf(sv[3]);
            p1.x = f2bf(sv[4]); p1.y = f2bf(sv[5]); p1.z = f2bf(sv[6]); p1.w = f2bf(sv[7]);
            *reinterpret_cast<ushort4*>(&PL[row * 72 + c8]) = p0;
            *reinterpret_cast<ushort4*>(&PL[row * 72 + c8 + 4]) = p1;
            if ((t & 7) == 0) {
                lL[row] = lL[row] * alpha + s;
                mL[row] = mnew;
                aL[row] = alpha;
            }
        }
        __syncthreads();
        float al[4];
        #pragma unroll
        for (int r = 0; r < 4; ++r) al[r] = aL[ih * 16 + quad * 4 + r];
        #pragma unroll
        for (int nt2 = 0; nt2 < 16; ++nt2)
            #pragma unroll
            for (int r = 0; r < 4; ++r) opv[nt2][r] *= al[r];
        #pragma unroll
        for (int kk = 0; kk < 2; ++kk) {
            bf8v pa = ld_bf8(&PL[(ih * 16 + l15) * 72 + kk * 32 + quad * 8]);
            #pragma unroll
            for (int nt2 = 0; nt2 < 16; ++nt2) {
                const u16* vp = vb + (size_t)(cb + nt2 * 16 + l15) * LL + j0 + kk * 32 + quad * 8;
                bf8v bv = ld_bf8(vp);
                opv[nt2] = __builtin_amdgcn_mfma_f32_16x16x32_bf16(pa, bv, opv[nt2], 0, 0, 0);
            }
        }
        __syncthreads();
    }
    float il[4];
    #pragma unroll
    for (int r = 0; r < 4; ++r) il[r] = 1.f / lL[ih * 16 + quad * 4 + r];
    #pragma unroll
    for (int nt2 = 0; nt2 < 16; ++nt2) {
        #pragma unroll
        for (int r = 0; r < 4; ++r) {
            int irow = ih * 16 + quad * 4 + r;
            h2T[((size_t)b * LL + i0 + irow) * D + cb + nt2 * 16 + l15] = f2bf(opv[nt2][r] * il[r]);
        }
    }
}

extern "C" void kernel_launch(void* const* d_in, const int* in_sizes, int n_in,
                              void* d_out, int out_size, void* d_ws, size_t ws_size,
                              hipStream_t stream) {
    const float* x   = (const float*)d_in[0];
    const float* gsc = (const float*)d_in[1];
    const float* gbi = (const float*)d_in[2];
    const float* wq  = (const float*)d_in[3];
    const float* bq  = (const float*)d_in[4];
    const float* wk  = (const float*)d_in[5];
    const float* bk  = (const float*)d_in[6];
    const float* wv  = (const float*)d_in[7];
    const float* bv  = (const float*)d_in[8];
    const float* wp  = (const float*)d_in[9];
    const float* bp  = (const float*)d_in[10];
    float* out = (float*)d_out;

    char* ws = (char*)d_ws;
    const size_t SZ   = (size_t)BB * LL * CC * 2;     // 16 MiB per [b][l][c] bf16 buffer
    const size_t WQSZ = (size_t)4 * CC * CC * 2;      // 2 MiB bf16 weights (q,k,v,p rows)
    const size_t SSZ  = (size_t)BB * LL * LL * 2;     // 128 MiB bf16 scores (all batches)
    const size_t RSZ  = (size_t)BB * LL * 4;          // 64 KiB f32 rowsums
    u16* bufA = (u16*)(ws);                  // hT -> h2T
    u16* bufB = (u16*)(ws + SZ);             // qT
    u16* bufC = (u16*)(ws + 2 * SZ);         // kT
    u16* bufD = (u16*)(ws + 3 * SZ);         // vv ([b][c][l])
    u16* wbf  = (u16*)(ws + 4 * SZ);
    float2* stats = (float2*)(ws + 4 * SZ + WQSZ);
    float* bcat   = (float*)(ws + 4 * SZ + WQSZ + 4096);
    float* rowsum = (float*)(ws + 4 * SZ + WQSZ + 4096 + 8192);
    u16* Sbuf = (u16*)(ws + 4 * SZ + WQSZ + 4096 + 8192 + RSZ);
    const size_t NEEDED = 4 * SZ + WQSZ + 4096 + 8192 + RSZ + SSZ;
    const float scale = 0.044194173824159216f;        // 512^-0.5
    const size_t BLC = (size_t)LL * CC;

    wconv_kernel<<<dim3(256, 4), 256, 0, stream>>>(wq, wk, wv, wp, wbf);
    biascat_kernel<<<dim3(6), 256, 0, stream>>>(bq, bk, bv, bcat);
    gn_stats_kernel<<<dim3(NG, BB), 256, 0, stream>>>(x, stats);
    gn_norm_t_kernel<<<dim3(64, 8, BB), 256, 0, stream>>>(x, stats, gsc, gbi, bufA);
    // fused QKV: nt 0-3 -> qT(bufB), 4-7 -> kT(bufC), 8-11 -> vv(bufD, transposed)
    gemm_kernel<0><<<dim3(32, 12, BB), 256, 0, stream>>>(bufA, BLC, CC, wbf, 0, CC, bcat, 1.f,
                                                         bufB, bufC, bufD, BLC, nullptr, nullptr,
                                                         CC, CC, nullptr);
    if (ws_size >= NEEDED) {
        // Two-pass attention, softmax fused into GEMM epilogues:
        //   P' = exp(QK^T*scale) with atomic rowsums; O = (P' V) / rowsum
        zero_kernel<<<dim3((BB * LL + 255) / 256), 256, 0, stream>>>(rowsum, BB * LL);
        gemm_kernel<1><<<dim3(32, 32, BB), 256, 0, stream>>>(bufB, BLC, CC, bufC, BLC, CC,
                                                             nullptr, scale, Sbuf, nullptr, nullptr,
                                                             (size_t)LL * LL, nullptr, nullptr,
                                                             LL, CC, rowsum);
        gemm_kernel<2><<<dim3(32, 4, BB), 256, 0, stream>>>(Sbuf, (size_t)LL * LL, LL, bufD, BLC, LL,
                                                            nullptr, 1.f, bufA, nullptr, nullptr,
                                                            BLC, nullptr, nullptr,
                                                            CC, LL, rowsum);
    } else {
        // Fallback: flash attention
        attn_kernel<<<dim3(LL / 32, BB), 256, 0, stream>>>(bufB, bufC, bufD, bufA);
    }
    // proj + residual + transposed f32 store
    gemm_kernel<3><<<dim3(32, 4, BB), 256, 0, stream>>>(bufA, BLC, CC, wbf + 3 * CC * CC, 0, CC,
                                                        bp, 1.f, nullptr, nullptr, nullptr,
                                                        0, x, out, CC, CC, nullptr);
}

// Round 8
// 325.110 us; speedup vs baseline: 1.2344x; 1.1188x over previous
//
#include <hip/hip_runtime.h>
#include <math.h>

// Shapes (fixed by the problem): b=4, c=512, l=4096, 32 groups.
// Inputs/outputs are float32; internal path: bf16 MFMA for QKV/proj,
// fp8 e4m3 MFMA for the two attention GEMMs (S = QK^T, O = P'V).
#define BB 4
#define CC 512
#define LL 4096
#define NG 32
#define CPG 16
#define EPSV 1e-6f

typedef short s16x8 __attribute__((ext_vector_type(8)));
typedef __bf16 bf8v __attribute__((ext_vector_type(8)));
typedef float f32x4 __attribute__((ext_vector_type(4)));
typedef unsigned short u16;
typedef unsigned char u8;

typedef const __attribute__((address_space(1))) void g1_void;
typedef __attribute__((address_space(3))) void l3_void;

// raw barrier / waitcnt (memory clobber = compiler reorder fence, no vmcnt drain)
#define ASM_SBAR() asm volatile("s_barrier" ::: "memory")
#define ASM_WAITV(N) asm volatile("s_waitcnt vmcnt(" #N ")" ::: "memory")

static __device__ __forceinline__ float bf2f(u16 h) {
    unsigned int u = ((unsigned int)h) << 16;
    union { unsigned int u; float f; } c; c.u = u; return c.f;
}
static __device__ __forceinline__ u16 f2bf(float f) {
    union { float f; unsigned int u; } c; c.f = f;
    unsigned int lsb = (c.u >> 16) & 1u;
    c.u += 0x7fffu + lsb;           // round-to-nearest-even
    return (u16)(c.u >> 16);
}
static __device__ __forceinline__ u8 f2fp8(float f) {
    int v = __builtin_amdgcn_cvt_pk_fp8_f32(f, f, 0, false);  // OCP e4m3fn, saturating
    return (u8)(v & 0xff);
}
static __device__ __forceinline__ bf8v ld_bf8(const u16* p) {
    return *reinterpret_cast<const bf8v*>(p);
}
// async global->LDS; HW writes lds_base + lane*16 (wave-uniform base required)
static __device__ __forceinline__ void gload16(const u16* g, u16* l) {
    __builtin_amdgcn_global_load_lds((g1_void*)g, (l3_void*)l, 16, 0, 0);
}
static __device__ __forceinline__ void gload16b(const u8* g, u8* l) {
    __builtin_amdgcn_global_load_lds((g1_void*)g, (l3_void*)l, 16, 0, 0);
}

// ---------------- zero rowsum buffer ----------------
__global__ __launch_bounds__(256) void zero_kernel(float* __restrict__ p, int n) {
    int i = blockIdx.x * 256 + threadIdx.x;
    if (i < n) p[i] = 0.f;
}

// ---------------- weight convert: four 512x512 f32 -> bf16 (rows: q,k,v,p) ----------------
__global__ __launch_bounds__(256) void wconv_kernel(const float* __restrict__ w0,
                                                    const float* __restrict__ w1,
                                                    const float* __restrict__ w2,
                                                    const float* __restrict__ w3,
                                                    u16* __restrict__ wbf) {
    int i = blockIdx.x * 256 + threadIdx.x;      // 0..65535 float4 chunks
    int wsel = blockIdx.y;
    const float* src = (wsel == 0) ? w0 : (wsel == 1) ? w1 : (wsel == 2) ? w2 : w3;
    float4 v = reinterpret_cast<const float4*>(src)[i];
    ushort4 o;
    o.x = f2bf(v.x); o.y = f2bf(v.y); o.z = f2bf(v.z); o.w = f2bf(v.w);
    reinterpret_cast<ushort4*>(wbf + (size_t)wsel * CC * CC)[i] = o;
}

// ---------------- concat q/k/v biases into one f32[1536] ----------------
__global__ __launch_bounds__(256) void biascat_kernel(const float* __restrict__ bq,
                                                      const float* __restrict__ bk,
                                                      const float* __restrict__ bv,
                                                      float* __restrict__ bcat) {
    int i = blockIdx.x * 256 + threadIdx.x;
    if (i >= 3 * CC) return;
    float v = (i < CC) ? bq[i] : (i < 2 * CC ? bk[i - CC] : bv[i - 2 * CC]);
    bcat[i] = v;
}

// ---------------- GroupNorm stats: one block per (group, batch) ----------------
__global__ __launch_bounds__(256) void gn_stats_kernel(const float* __restrict__ x,
                                                       float2* __restrict__ stats) {
    int g = blockIdx.x, b = blockIdx.y, t = threadIdx.x;
    const float4* xp = reinterpret_cast<const float4*>(x + ((size_t)b * CC + (size_t)g * CPG) * LL);
    float s = 0.f, ss = 0.f;
    for (int it = 0; it < 64; ++it) {
        float4 v = xp[it * 256 + t];
        s += v.x + v.y + v.z + v.w;
        ss += v.x * v.x + v.y * v.y + v.z * v.z + v.w * v.w;
    }
    #pragma unroll
    for (int off = 32; off; off >>= 1) { s += __shfl_xor(s, off, 64); ss += __shfl_xor(ss, off, 64); }
    __shared__ float rs[4], rss[4];
    int wave = t >> 6, lane = t & 63;
    if (lane == 0) { rs[wave] = s; rss[wave] = ss; }
    __syncthreads();
    if (t == 0) {
        float S = rs[0] + rs[1] + rs[2] + rs[3];
        float SS = rss[0] + rss[1] + rss[2] + rss[3];
        float mean = S * (1.f / 65536.f);
        float var = SS * (1.f / 65536.f) - mean * mean;
        var = fmaxf(var, 0.f);
        stats[b * NG + g] = make_float2(mean, rsqrtf(var + EPSV));
    }
}

// -------- GroupNorm normalize + transpose: x[b][c][l] f32 -> hT[b][l][c] bf16 --------
__global__ __launch_bounds__(256) void gn_norm_t_kernel(const float* __restrict__ x,
                                                        const float2* __restrict__ stats,
                                                        const float* __restrict__ gsc,
                                                        const float* __restrict__ gbi,
                                                        u16* __restrict__ hT) {
    int lt = blockIdx.x, ct = blockIdx.y, b = blockIdx.z;
    __shared__ u16 tile[64][72];
    int t = threadIdx.x;
    int cl0 = t >> 4, c4 = (t & 15) * 4;
    #pragma unroll
    for (int p = 0; p < 4; ++p) {
        int cl = p * 16 + cl0;
        int cg = ct * 64 + cl;
        float2 st = stats[b * NG + (cg >> 4)];
        float sc = gsc[cg] * st.y;
        float bi = gbi[cg];
        float4 v = *reinterpret_cast<const float4*>(x + ((size_t)b * CC + cg) * LL + lt * 64 + c4);
        tile[cl][c4 + 0] = f2bf((v.x - st.x) * sc + bi);
        tile[cl][c4 + 1] = f2bf((v.y - st.x) * sc + bi);
        tile[cl][c4 + 2] = f2bf((v.z - st.x) * sc + bi);
        tile[cl][c4 + 3] = f2bf((v.w - st.x) * sc + bi);
    }
    __syncthreads();
    int r = t >> 3, c8 = (t & 7) * 8;
    #pragma unroll
    for (int p = 0; p < 2; ++p) {
        int ll = p * 32 + r;
        s16x8 ov;
        #pragma unroll
        for (int j = 0; j < 8; ++j) ov[j] = (short)tile[c8 + j][ll];
        u16* hp = hT + ((size_t)b * LL + lt * 64 + ll) * CC + ct * 64 + c8;
        *reinterpret_cast<s16x8*>(hp) = ov;
    }
}

// ---------------- bf16 GEMM: Out = A * B^T + bias ----------------
// MODE 0: fused QKV, fp8 outputs. nt/4==0 -> q8 [l][c], ==1 -> k8 [l][c],
//         ==2 -> v8 stored TRANSPOSED [c][l].
// MODE 3: proj: + bias, TRANSPOSED f32 store with residual: fout = xres + val.
// Pipelined K-loop: 2 LDS buffers, prefetch distance 2, raw s_barrier + vmcnt(4)/0.
template <int MODE>
__global__ __launch_bounds__(256) void gemm_kernel(const u16* __restrict__ A, size_t asb, int lda,
                                                   const u16* __restrict__ B, size_t bsb, int ldb,
                                                   const float* __restrict__ bias,
                                                   u8* __restrict__ Oq, u8* __restrict__ Ok,
                                                   u8* __restrict__ Ov, size_t osb,
                                                   const float* __restrict__ xres,
                                                   float* __restrict__ fout, int K) {
    // staging 2 x (A 8KB + B 8KB) = 32 KB; epilogue: fp8 tile 128*144 = 18432 B (MODE 0)
    // or bf16 round-trip (MODE 3) 128*136*2 = 34816 B
    __shared__ u16 pool[17408];
    u8* pool8 = (u8*)pool;
    int mt = blockIdx.x, nt = blockIdx.y, b = blockIdx.z;
    int t = threadIdx.x;
    int wave = t >> 6, lane = t & 63;
    int wm = (wave >> 1) * 64, wn = (wave & 1) * 64;
    int l15 = lane & 15, quad = lane >> 4;
    f32x4 acc[4][4] = {};
    const u16* Ab = A + (size_t)b * asb + (size_t)mt * 128 * lda;
    const u16* Bb = B + (size_t)b * bsb + (size_t)nt * 128 * ldb;
    int swzg = ((lane & 3) ^ ((lane >> 2) & 3) ^ ((lane >> 4) & 3)) * 8;
    int row0 = wave * 16 + (lane >> 2);
    int row1 = 64 + row0;
    const u16* Ap0 = Ab + (size_t)row0 * lda + swzg;
    const u16* Ap1 = Ab + (size_t)row1 * lda + swzg;
    const u16* Bp0 = Bb + (size_t)row0 * ldb + swzg;
    const u16* Bp1 = Bb + (size_t)row1 * ldb + swzg;
    int wo = wave * 512;
    int swzf = (l15 & 3) ^ (l15 >> 2);
    int aoff = (wm + l15) * 32 + ((quad ^ swzf) * 8);
    int boff = (wn + l15) * 32 + ((quad ^ swzf) * 8);
    const int iters = K >> 5;
    gload16(Ap0, pool + wo);                gload16(Ap1, pool + 2048 + wo);
    gload16(Bp0, pool + 8192 + wo);         gload16(Bp1, pool + 8192 + 2048 + wo);
    gload16(Ap0 + 32, pool + 4096 + wo);    gload16(Ap1 + 32, pool + 4096 + 2048 + wo);
    gload16(Bp0 + 32, pool + 12288 + wo);   gload16(Bp1 + 32, pool + 12288 + 2048 + wo);
    for (int i = 0; i < iters; ++i) {
        if (i + 1 < iters) { ASM_WAITV(4); } else { ASM_WAITV(0); }
        ASM_SBAR();
        int bs = (i & 1) * 4096;
        const u16* As = pool + bs;
        const u16* Bs = pool + 8192 + bs;
        bf8v af[4], bfr[4];
        #pragma unroll
        for (int ii = 0; ii < 4; ++ii)
            af[ii] = ld_bf8(&As[aoff + ii * 512]);
        #pragma unroll
        for (int j = 0; j < 4; ++j)
            bfr[j] = ld_bf8(&Bs[boff + j * 512]);
        #pragma unroll
        for (int ii = 0; ii < 4; ++ii)
            #pragma unroll
            for (int j = 0; j < 4; ++j)
                acc[ii][j] = __builtin_amdgcn_mfma_f32_16x16x32_bf16(af[ii], bfr[j], acc[ii][j], 0, 0, 0);
        ASM_SBAR();
        if (i + 2 < iters) {
            int kk = (i + 2) * 32;
            u16* as = pool + bs; u16* bsp = pool + 8192 + bs;
            gload16(Ap0 + kk, as + wo);        gload16(Ap1 + kk, as + 2048 + wo);
            gload16(Bp0 + kk, bsp + wo);       gload16(Bp1 + kk, bsp + 2048 + wo);
        }
    }
    __syncthreads();
    if (MODE == 0) {
        int nt_sel = nt >> 2, ntl = nt & 3;
        bool transT = (nt_sel == 2);
        #pragma unroll
        for (int j = 0; j < 4; ++j) {
            float bv = bias[nt * 128 + wn + j * 16 + l15];
            #pragma unroll
            for (int i = 0; i < 4; ++i) {
                if (transT) {
                    // pack 4 rows (r) into one u32 at [col][row..row+3]
                    int col = wn + j * 16 + l15;
                    int row = wm + i * 16 + quad * 4;
                    unsigned int w = __builtin_amdgcn_cvt_pk_fp8_f32(acc[i][j][0] + bv, acc[i][j][1] + bv, 0, false);
                    w = __builtin_amdgcn_cvt_pk_fp8_f32(acc[i][j][2] + bv, acc[i][j][3] + bv, w, true);
                    *reinterpret_cast<unsigned int*>(&pool8[col * 144 + row]) = w;
                } else {
                    #pragma unroll
                    for (int r = 0; r < 4; ++r) {
                        int row = wm + i * 16 + quad * 4 + r;
                        int col = wn + j * 16 + l15;
                        pool8[row * 144 + col] = f2fp8(acc[i][j][r] + bv);
                    }
                }
            }
        }
        __syncthreads();
        u8* Ob; int rstride;
        if (nt_sel == 0)      { Ob = Oq + (size_t)b * osb + (size_t)(mt * 128) * CC + ntl * 128; rstride = CC; }
        else if (nt_sel == 1) { Ob = Ok + (size_t)b * osb + (size_t)(mt * 128) * CC + ntl * 128; rstride = CC; }
        else                  { Ob = Ov + (size_t)b * osb + (size_t)(ntl * 128) * LL + mt * 128; rstride = LL; }
        #pragma unroll
        for (int it = 0; it < 4; ++it) {
            int idx = it * 256 + t;
            int row = idx >> 3, ch = (idx & 7) * 16;
            *reinterpret_cast<float4*>(Ob + (size_t)row * rstride + ch) =
                *reinterpret_cast<const float4*>(&pool8[row * 144 + ch]);
        }
    } else {
        // MODE 3: bf16 tile (stride 136 u16) -> residual + f32 transposed store
        #pragma unroll
        for (int j = 0; j < 4; ++j) {
            float bv = bias[nt * 128 + wn + j * 16 + l15];
            #pragma unroll
            for (int i = 0; i < 4; ++i)
                #pragma unroll
                for (int r = 0; r < 4; ++r) {
                    int row = wm + i * 16 + quad * 4 + r;
                    int col = wn + j * 16 + l15;
                    pool[col * 136 + row] = f2bf(acc[i][j][r] + bv);
                }
        }
        __syncthreads();
        const float* xb = xres + ((size_t)b * CC + nt * 128) * LL + mt * 128;
        float* ob = fout + ((size_t)b * CC + nt * 128) * LL + mt * 128;
        #pragma unroll
        for (int it = 0; it < 16; ++it) {
            int idx = it * 256 + t;
            int cl = idx >> 5, ch = (idx & 31) * 4;
            short4 pv = *reinterpret_cast<const short4*>(&pool[cl * 136 + ch]);
            float4 xv = *reinterpret_cast<const float4*>(xb + (size_t)cl * LL + ch);
            float4 ov;
            ov.x = xv.x + bf2f((u16)pv.x);
            ov.y = xv.y + bf2f((u16)pv.y);
            ov.z = xv.z + bf2f((u16)pv.z);
            ov.w = xv.w + bf2f((u16)pv.w);
            *reinterpret_cast<float4*>(ob + (size_t)cl * LL + ch) = ov;
        }
    }
}

// ---------------- fp8 GEMM: Out = f(A * B^T) (attention S and PV passes) ----------------
// MODE 1 (S): A=q8 [l][c], B=k8 [l][c], P' = exp(acc*scale - 3) -> fp8 Out8 [i][j],
//             rowsum accumulated via per-row shuffle + atomicAdd. LDS 18432 B.
// MODE 2 (PV): A=P' fp8 [i][j], B=v8 [c][l]; out = acc / rowsum -> bf16 OutH [l][c].
// Staging: per 32-k chunk, tile = 128 rows x 32 B; lane covers 16 B at
// R = 32*wave + (lane>>1), global 16B-chunk c16 = (lane&1) ^ (R&1) ^ ((R>>2)&1)
// (bit-preserving swizzle so the 16B pair stays aligned; breaks 4-way frag conflicts).
template <int MODE>
__global__ __launch_bounds__(256) void gemm8_kernel(const u8* __restrict__ A, size_t asb, int lda,
                                                    const u8* __restrict__ B, size_t bsb, int ldb,
                                                    float scale,
                                                    u8* __restrict__ Out8, u16* __restrict__ OutH,
                                                    size_t osb, int Nout, int K,
                                                    float* __restrict__ rsum) {
    __shared__ u8 pool8[MODE == 1 ? 18432 : 34816];
    int mt = blockIdx.x, nt = blockIdx.y, b = blockIdx.z;
    int t = threadIdx.x;
    int wave = t >> 6, lane = t & 63;
    int wm = (wave >> 1) * 64, wn = (wave & 1) * 64;
    int l15 = lane & 15, quad = lane >> 4;
    f32x4 acc[4][4] = {};
    int R = wave * 32 + (lane >> 1);
    int c16 = ((lane & 1) ^ (R & 1) ^ ((R >> 2) & 1)) * 16;
    const u8* Ap = A + (size_t)b * asb + (size_t)(mt * 128 + R) * lda + c16;
    const u8* Bp = B + (size_t)b * bsb + (size_t)(nt * 128 + R) * ldb + c16;
    u8* ldsw = pool8 + wave * 1024;
    // fragment read: 8 B at row R' = base+l15, 8B-chunk quad (swizzled)
    int p = (l15 & 1) ^ ((l15 >> 2) & 1);
    int fo = (((quad >> 1) ^ p) * 16) + (quad & 1) * 8;
    int abase = (wm + l15) * 32 + fo;
    int bbase = (wn + l15) * 32 + fo;
    const int iters = K >> 5;
    gload16b(Ap, ldsw);                 gload16b(Bp, pool8 + 8192 + wave * 1024);
    gload16b(Ap + 32, pool8 + 4096 + wave * 1024);
    gload16b(Bp + 32, pool8 + 12288 + wave * 1024);
    for (int i = 0; i < iters; ++i) {
        if (i + 1 < iters) { ASM_WAITV(2); } else { ASM_WAITV(0); }
        ASM_SBAR();
        int bs = (i & 1) * 4096;
        const u8* As = pool8 + bs;
        const u8* Bs = pool8 + 8192 + bs;
        long af[4], bfr[4];
        #pragma unroll
        for (int ii = 0; ii < 4; ++ii)
            af[ii] = *reinterpret_cast<const long*>(As + abase + ii * 512);
        #pragma unroll
        for (int j = 0; j < 4; ++j)
            bfr[j] = *reinterpret_cast<const long*>(Bs + bbase + j * 512);
        #pragma unroll
        for (int ii = 0; ii < 4; ++ii)
            #pragma unroll
            for (int j = 0; j < 4; ++j)
                acc[ii][j] = __builtin_amdgcn_mfma_f32_16x16x32_fp8_fp8(af[ii], bfr[j], acc[ii][j], 0, 0, 0);
        ASM_SBAR();
        if (i + 2 < iters) {
            int kk = (i + 2) * 32;
            gload16b(Ap + kk, pool8 + bs + wave * 1024);
            gload16b(Bp + kk, pool8 + 8192 + bs + wave * 1024);
        }
    }
    __syncthreads();
    if (MODE == 1) {
        // P' = exp(acc*scale - 3): e4m3-safe (max ~e^2.5=12 << 448); rowsum from f32 vals
        #pragma unroll
        for (int i = 0; i < 4; ++i) {
            #pragma unroll
            for (int r = 0; r < 4; ++r) {
                int row = wm + i * 16 + quad * 4 + r;
                float part = 0.f;
                #pragma unroll
                for (int j = 0; j < 4; ++j) {
                    float v = __expf(acc[i][j][r] * scale - 3.0f);
                    part += v;
                    pool8[row * 144 + wn + j * 16 + l15] = f2fp8(v);
                }
                part += __shfl_xor(part, 1, 64);
                part += __shfl_xor(part, 2, 64);
                part += __shfl_xor(part, 4, 64);
                part += __shfl_xor(part, 8, 64);
                if (l15 == 0)
                    atomicAdd(rsum + (size_t)b * LL + mt * 128 + row, part);
            }
        }
        __syncthreads();
        u8* Ob = Out8 + (size_t)b * osb + (size_t)(mt * 128) * Nout + nt * 128;
        #pragma unroll
        for (int it = 0; it < 4; ++it) {
            int idx = it * 256 + t;
            int row = idx >> 3, ch = (idx & 7) * 16;
            *reinterpret_cast<float4*>(Ob + (size_t)row * Nout + ch) =
                *reinterpret_cast<const float4*>(&pool8[row * 144 + ch]);
        }
    } else {
        // MODE 2: normalize rows by 1/rowsum, bf16 out via LDS round-trip
        u16* poolh = (u16*)pool8;
        float invl[4][4];
        #pragma unroll
        for (int i = 0; i < 4; ++i)
            #pragma unroll
            for (int r = 0; r < 4; ++r)
                invl[i][r] = 1.f / rsum[(size_t)b * LL + mt * 128 + wm + i * 16 + quad * 4 + r];
        #pragma unroll
        for (int j = 0; j < 4; ++j)
            #pragma unroll
            for (int i = 0; i < 4; ++i)
                #pragma unroll
                for (int r = 0; r < 4; ++r) {
                    int row = wm + i * 16 + quad * 4 + r;
                    int col = wn + j * 16 + l15;
                    poolh[row * 136 + col] = f2bf(acc[i][j][r] * invl[i][r]);
                }
        __syncthreads();
        u16* Ob = OutH + (size_t)b * osb + (size_t)(mt * 128) * Nout + nt * 128;
        #pragma unroll
        for (int it = 0; it < 8; ++it) {
            int idx = it * 256 + t;
            int row = idx >> 4, ch = (idx & 15) * 8;
            s16x8 val = *reinterpret_cast<const s16x8*>(&poolh[row * 136 + ch]);
            *reinterpret_cast<s16x8*>(Ob + (size_t)row * Nout + ch) = val;
        }
    }
}

extern "C" void kernel_launch(void* const* d_in, const int* in_sizes, int n_in,
                              void* d_out, int out_size, void* d_ws, size_t ws_size,
                              hipStream_t stream) {
    const float* x   = (const float*)d_in[0];
    const float* gsc = (const float*)d_in[1];
    const float* gbi = (const float*)d_in[2];
    const float* wq  = (const float*)d_in[3];
    const float* bq  = (const float*)d_in[4];
    const float* wk  = (const float*)d_in[5];
    const float* bk  = (const float*)d_in[6];
    const float* wv  = (const float*)d_in[7];
    const float* bv  = (const float*)d_in[8];
    const float* wp  = (const float*)d_in[9];
    const float* bp  = (const float*)d_in[10];
    float* out = (float*)d_out;

    char* ws = (char*)d_ws;
    const size_t SZ   = (size_t)BB * LL * CC * 2;     // 16 MiB bf16 [b][l][c] (hT / h2T)
    const size_t QSZ  = (size_t)BB * LL * CC;         // 8 MiB fp8 per q/k/v buffer
    const size_t WQSZ = (size_t)4 * CC * CC * 2;      // 2 MiB bf16 weights
    const size_t RSZ  = (size_t)BB * LL * 4;          // 64 KiB f32 rowsums
    u16* bufA = (u16*)(ws);                           // hT, then h2T
    u8*  q8   = (u8*)(ws + SZ);
    u8*  k8   = (u8*)(ws + SZ + QSZ);
    u8*  v8   = (u8*)(ws + SZ + 2 * QSZ);             // [b][c][l] fp8
    u16* wbf  = (u16*)(ws + SZ + 3 * QSZ);
    float2* stats = (float2*)(ws + SZ + 3 * QSZ + WQSZ);
    float* bcat   = (float*)(ws + SZ + 3 * QSZ + WQSZ + 4096);
    float* rowsum = (float*)(ws + SZ + 3 * QSZ + WQSZ + 4096 + 8192);
    u8* S8 = (u8*)(ws + SZ + 3 * QSZ + WQSZ + 4096 + 8192 + RSZ);   // 64 MiB fp8 scores
    const float scale = 0.044194173824159216f;        // 512^-0.5
    const size_t BLC = (size_t)LL * CC;

    wconv_kernel<<<dim3(256, 4), 256, 0, stream>>>(wq, wk, wv, wp, wbf);
    biascat_kernel<<<dim3(6), 256, 0, stream>>>(bq, bk, bv, bcat);
    gn_stats_kernel<<<dim3(NG, BB), 256, 0, stream>>>(x, stats);
    gn_norm_t_kernel<<<dim3(64, 8, BB), 256, 0, stream>>>(x, stats, gsc, gbi, bufA);
    // fused QKV (bf16 compute, fp8 outputs): nt 0-3 -> q8, 4-7 -> k8, 8-11 -> v8^T
    gemm_kernel<0><<<dim3(32, 12, BB), 256, 0, stream>>>(bufA, BLC, CC, wbf, 0, CC, bcat,
                                                         q8, k8, v8, BLC, nullptr, nullptr, CC);
    // attention: P' = exp(QK^T*scale - 3) fp8 + rowsums; O = (P' V) / rowsum
    zero_kernel<<<dim3((BB * LL + 255) / 256), 256, 0, stream>>>(rowsum, BB * LL);
    gemm8_kernel<1><<<dim3(32, 32, BB), 256, 0, stream>>>(q8, BLC, CC, k8, BLC, CC, scale,
                                                          S8, nullptr, (size_t)LL * LL, LL, CC, rowsum);
    gemm8_kernel<2><<<dim3(32, 4, BB), 256, 0, stream>>>(S8, (size_t)LL * LL, LL, v8, BLC, LL, 1.f,
                                                         nullptr, bufA, BLC, CC, LL, rowsum);
    // proj + residual + transposed f32 store
    gemm_kernel<3><<<dim3(32, 4, BB), 256, 0, stream>>>(bufA, BLC, CC, wbf + 3 * CC * CC, 0, CC,
                                                        bp, nullptr, nullptr, nullptr, 0, x, out, CC);
}